// Round 16
// baseline (501.393 us; speedup 1.0000x reference)
//
#include <hip/hip_runtime.h>
#include <stdint.h>

typedef __attribute__((ext_vector_type(8)))  short s16x8;   // 8 x bf16
typedef __attribute__((ext_vector_type(16))) float f32x16;  // 32x32 MFMA acc
typedef __attribute__((ext_vector_type(2)))  unsigned u32x2;

union CvtI4 { int4 i; s16x8 s; };
union CvtU4 { uint4 u; s16x8 s; };

__device__ __forceinline__ unsigned f2bf(float f) {
    union { float f; unsigned u; } v; v.f = f;
    return (v.u + 0x7fffu + ((v.u >> 16) & 1u)) >> 16;     // RNE
}

// pack two f32 -> (bf16(lo) | bf16(hi)<<16), round-half-up (v12-verified idiom)
__device__ __forceinline__ unsigned packbf(float lo, float hi) {
    union { float f; unsigned u; } a0, a1;
    a0.f = lo; a1.f = hi;
    return __builtin_amdgcn_perm(a1.u + 0x8000u, a0.u + 0x8000u, 0x07060302u);
}

// ---------------------------------------------------------------------------
// k_prep v3: emits MFMA fragment-order layouts (for the barrier-free attn).
//   xTf:  [b][st=n>>5][kk=0..3][lane=0..63] 16B blocks; lane l = (n&31)+32*hb
//         holds bf16(x*QS) for row n, c = 16*kk + 8*hb + e  (A/B frag order).
//   vbff: [b][tile=n>>6][s][ksl][dl][lane] 16B blocks; lane l = (d&31)+32*hb
//         holds relu(bn1(w1.x)) for d-row, m = tile*64+(s*4+ksl*2+hb)*8+e.
// Values identical to the old xT/vbf; only addresses changed (verified maps).
// grid 1024 = (b, n0g, half), 256 thr.
// ---------------------------------------------------------------------------
__global__ __launch_bounds__(256) void k_prep(
    const float* __restrict__ x, const float* __restrict__ w1,
    const float* __restrict__ g1, const float* __restrict__ b1,
    const float* __restrict__ m1, const float* __restrict__ v1,
    unsigned short* __restrict__ xTf, unsigned short* __restrict__ vbff)
{
    __shared__ float X[64 * 65];   // [c][n] pad+1
    const int b    = blockIdx.x >> 7;
    const int n0g  = (blockIdx.x >> 1) & 63;
    const int n0   = n0g << 6;
    const int half = blockIdx.x & 1;
    const int tid  = threadIdx.x;
    const float QS = 0.42466090014400953f;   // sqrt(log2(e)/8)

    {
        const int r = tid >> 6, nn = tid & 63;
        const float* xb = x + (size_t)b * 262144 + n0 + nn;
#pragma unroll
        for (int cc = 0; cc < 16; ++cc) {
            int c = cc * 4 + r;
            X[c * 65 + nn] = xb[(size_t)c * 4096];
        }
    }
    __syncthreads();

    {   // xTf fragment write: thread (n8, c8) -> block (st, kk=c8>>1), lane n8+32*(c8&1)
        const int n8 = tid >> 3, c8 = tid & 7;
        const int kk = c8 >> 1, hb = c8 & 1;
        const int st = (n0g << 1) + half;         // global 32-row strip
        const int N  = (half << 5) + n8;          // local row in X
        unsigned u[4];
#pragma unroll
        for (int j = 0; j < 4; ++j) {
            unsigned lo = f2bf(X[(c8 * 8 + 2 * j) * 65 + N] * QS);
            unsigned hi = f2bf(X[(c8 * 8 + 2 * j + 1) * 65 + N] * QS);
            u[j] = lo | (hi << 16);
        }
        uint4 pk; pk.x = u[0]; pk.y = u[1]; pk.z = u[2]; pk.w = u[3];
        *(uint4*)(xTf + ((((size_t)((b << 7) + st) << 2) + kk) << 9)
                      + ((n8 + (hb << 5)) << 3)) = pk;
    }

    {   // vbff fragment write: V = relu(bn1(conv1x1)), d-half = half
        const int n = tid & 63, og = tid >> 6;
        float rX[64];
#pragma unroll
        for (int c = 0; c < 64; ++c) rX[c] = X[c * 65 + n];
        const int cn = n >> 3, e = n & 7;
        const int sS = cn >> 2, kslS = (cn >> 1) & 1, hb = cn & 1;
        unsigned short* vb = vbff +
            ((((size_t)((b << 6) + n0g) << 3) + (sS << 2) + (kslS << 1) + half) << 9) + e;
#pragma unroll 2
        for (int oo = 0; oo < 8; ++oo) {
            int o = (half << 5) + og * 8 + oo;
            float inv = g1[o] * rsqrtf(v1[o] + 1e-5f);
            float sh  = b1[o] - m1[o] * inv;
            float acc = 0.f;
#pragma unroll
            for (int c = 0; c < 64; ++c) acc = fmaf(w1[o * 64 + c], rX[c], acc);
            int lane = (og * 8 + oo) + (hb << 5);
            vb[lane << 3] = (unsigned short)f2bf(fmaxf(fmaf(acc, inv, sh), 0.f));
        }
    }
}

// ---------------------------------------------------------------------------
// k_attn v25: v21 body (barrier-free streaming, 49.2us verified) at DOUBLE
// occupancy. R14 accounting: v21 at 4 waves/SIMD leaves ~1000cy/iter of
// dependency bubbles (serial QK->exp2->PV chain) that TLP could fill; its
// footprint (VGPR 52 <= 64-cap, LDS 68KB <= 80KB) fits 8 waves/SIMD
// exactly. v25 halves the q-range per block: grid 512 = (b=XCD, qg of
// 64 q), 16 waves = (s, t2 in {0,1}) x par in {0..3}; wave streams 16
// tile-jobs T = 4*it+par with the v21-verbatim body (rotation dropped --
// R14 proved null). Epilogue: 3-step par-tree (4 partials) + s-merge in
// the same 64KB scratch. launch_bounds(1024,8) pins VGPR at 64 (12 spare).
// Falsifier: WRITE_SIZE balloons => cap-forced spill => revert to v21.
// ---------------------------------------------------------------------------
__global__ __launch_bounds__(1024, 8) void k_attn(
    const unsigned short* __restrict__ xTf, const unsigned short* __restrict__ vbff,
    unsigned short* __restrict__ outO)
{
    __shared__ float scr[16384];      // 64KB epilogue scratch (unused in main loop)
    __shared__ float rsL[16][32];
    __shared__ float dnm[64];

    const int b   = blockIdx.x & 7;           // batch == XCD slice
    const int qg  = blockIdx.x >> 3;          // 0..63 (64-q group)
    const int tid = threadIdx.x;
    const int w = tid >> 6, lane = tid & 63;
    const int l31 = lane & 31, half = lane >> 5;
    const int qbase = qg << 6;
    const int qd = w & 3, par = w >> 2;       // par in {0..3}
    const int s  = qd & 1;     // m-strip (QK) / PV m-chunk group
    const int t2 = qd >> 1;    // n-slab (0..1), 32 q rows each

    // ---- Q fragments: blocks (st_q = qg*2 + t2, kk) ----
    s16x8 Bq[4];
    {
        const unsigned short* qB = xTf +
            (((size_t)((b << 7) + (qg << 1) + t2)) << 11) + (lane << 3);
#pragma unroll
        for (int kk = 0; kk < 4; ++kk) {
            CvtI4 c; c.i = *(const int4*)(qB + (kk << 9));
            Bq[kk] = c.s;
        }
    }

    // ---- streaming bases: block idx = b*512 + T*8 + s*4 + j, T-stride 4096 ----
    const unsigned short* akB = xTf  + (((size_t)((b << 9) + (s << 2))) << 9) + (lane << 3);
    const unsigned short* bvB = vbff + (((size_t)((b << 9) + (s << 2))) << 9) + (lane << 3);

    f32x16 O[2];
#pragma unroll
    for (int dl = 0; dl < 2; ++dl)
#pragma unroll
        for (int r = 0; r < 16; ++r) O[dl][r] = 0.f;
    float rs = 0.f;

    // ========== main loop: 16 tile-jobs (T = 4*it+par), NO barriers ========
    for (int it = 0; it < 16; ++it) {
        const size_t toff = ((size_t)((it << 2) + par)) << 12;   // T*4096 ushorts

        int4 ar[4], br[4];
#pragma unroll
        for (int kk = 0; kk < 4; ++kk) ar[kk] = *(const int4*)(akB + (kk << 9) + toff);
#pragma unroll
        for (int j = 0; j < 4; ++j)    br[j]  = *(const int4*)(bvB + (j << 9) + toff);

        // ---- QK quadrant (s,t2) of tile T ----
        f32x16 S = {0.f,0.f,0.f,0.f,0.f,0.f,0.f,0.f,0.f,0.f,0.f,0.f,0.f,0.f,0.f,0.f};
        __builtin_amdgcn_s_setprio(1);
        {
            CvtI4 c0; c0.i = ar[0]; S = __builtin_amdgcn_mfma_f32_32x32x16_bf16(c0.s, Bq[0], S, 0, 0, 0);
            CvtI4 c1; c1.i = ar[1]; S = __builtin_amdgcn_mfma_f32_32x32x16_bf16(c1.s, Bq[1], S, 0, 0, 0);
            CvtI4 c2; c2.i = ar[2]; S = __builtin_amdgcn_mfma_f32_32x32x16_bf16(c2.s, Bq[2], S, 0, 0, 0);
            CvtI4 c3; c3.i = ar[3]; S = __builtin_amdgcn_mfma_f32_32x32x16_bf16(c3.s, Bq[3], S, 0, 0, 0);
        }
        __builtin_amdgcn_s_setprio(0);

        // ---- exp2 + pack to bf16 pairs (m-group q, lane-local in n) ----
        uint2 G[4];
#pragma unroll
        for (int q = 0; q < 4; ++q) {
            float p0 = __builtin_amdgcn_exp2f(S[4*q+0]);
            float p1 = __builtin_amdgcn_exp2f(S[4*q+1]);
            float p2 = __builtin_amdgcn_exp2f(S[4*q+2]);
            float p3 = __builtin_amdgcn_exp2f(S[4*q+3]);
            rs += (p0 + p1) + (p2 + p3);
            G[q].x = packbf(p0, p1);
            G[q].y = packbf(p2, p3);
        }

        // ---- PV: in-register P via permlane32_swap; B = streamed V frags ----
        __builtin_amdgcn_s_setprio(1);
#pragma unroll
        for (int ksl = 0; ksl < 2; ++ksl) {
            // swap(a,b) -> r.x = a.lo||b.lo (dw-low), r.y = a.hi||b.hi (dw-high)
            u32x2 r0 = __builtin_amdgcn_permlane32_swap(G[2*ksl].x, G[2*ksl+1].x, false, false);
            u32x2 r1 = __builtin_amdgcn_permlane32_swap(G[2*ksl].y, G[2*ksl+1].y, false, false);
            CvtU4 ac;
            ac.u.x = r0.x; ac.u.y = r1.x; ac.u.z = r0.y; ac.u.w = r1.y;
            const s16x8 Ap = ac.s;
            CvtI4 v0; v0.i = br[2*ksl + 0];
            CvtI4 v1; v1.i = br[2*ksl + 1];
            O[0] = __builtin_amdgcn_mfma_f32_32x32x16_bf16(Ap, v0.s, O[0], 0, 0, 0);
            O[1] = __builtin_amdgcn_mfma_f32_32x32x16_bf16(Ap, v1.s, O[1], 0, 0, 0);
        }
        __builtin_amdgcn_s_setprio(0);
    }

    // ========= epilogue: par-tree (4 partials) -> s-merge -> store =========
    rs += __shfl_xor(rs, 32);
    if (half == 0) rsL[w][l31] = rs;

    // step 1: par 2,3 write regions qd*2 + (par&1)  (8 regions x 2048 f32)
    if (par >= 2) {
        float* rg = scr + (((qd << 1) + (par & 1)) << 11);
#pragma unroll
        for (int dl = 0; dl < 2; ++dl)
#pragma unroll
            for (int r = 0; r < 16; ++r)
                rg[(dl << 10) + (r << 6) + lane] = O[dl][r];
    }
    __syncthreads();

    if (tid < 64) {      // denom: 8 contributing waves per n-slab
        int t2v = tid >> 5, n32 = tid & 31;
        float a = 0.f;
#pragma unroll
        for (int pp = 0; pp < 4; ++pp)
            a += rsL[(pp << 2) + (t2v << 1) + 0][n32] +
                 rsL[(pp << 2) + (t2v << 1) + 1][n32];
        dnm[tid] = a;
    }
    if (par < 2) {       // par 0 += par 2 ; par 1 += par 3
        float* rg = scr + (((qd << 1) + par) << 11);
#pragma unroll
        for (int dl = 0; dl < 2; ++dl)
#pragma unroll
            for (int r = 0; r < 16; ++r)
                O[dl][r] += rg[(dl << 10) + (r << 6) + lane];
    }
    __syncthreads();

    // step 2: par 1 writes region qd (0..3)
    if (par == 1) {
        float* rg = scr + (qd << 11);
#pragma unroll
        for (int dl = 0; dl < 2; ++dl)
#pragma unroll
            for (int r = 0; r < 16; ++r)
                rg[(dl << 10) + (r << 6) + lane] = O[dl][r];
    }
    __syncthreads();

    // step 3: par 0 adds (full par-sum); s==1 writes region 4+t2
    if (par == 0) {
        float* rg = scr + (qd << 11);
#pragma unroll
        for (int dl = 0; dl < 2; ++dl)
#pragma unroll
            for (int r = 0; r < 16; ++r)
                O[dl][r] += rg[(dl << 10) + (r << 6) + lane];
        if (s == 1) {
            float* rg2 = scr + ((4 + t2) << 11);
#pragma unroll
            for (int dl = 0; dl < 2; ++dl)
#pragma unroll
                for (int r = 0; r < 16; ++r)
                    rg2[(dl << 10) + (r << 6) + lane] = O[dl][r];
        }
    }
    __syncthreads();

    // step 4: par 0, s 0: final sum, normalize, store
    if (par == 0 && s == 0) {
        const int nb = (b << 12) + qbase;
        float* rg2 = scr + ((4 + t2) << 11);
#pragma unroll
        for (int dl = 0; dl < 2; ++dl)
#pragma unroll
            for (int r = 0; r < 16; ++r) {
                int rowoff = (r & 3) + ((r >> 2) << 3) + (half << 2);
                int n = (t2 << 5) + rowoff;
                float o = O[dl][r] + rg2[(dl << 10) + (r << 6) + lane];
                outO[((size_t)(nb + n) << 6) + (dl << 5) + l31] =
                    (unsigned short)f2bf(o * (1.f / dnm[n]));
            }
    }
}

// ---------------------------------------------------------------------------
// k_post v2: w-half split. grid 1024 = (b, h, wh), 256 thr.
// ---------------------------------------------------------------------------
__global__ __launch_bounds__(256) void k_post(
    const unsigned short* __restrict__ Obase,
    const float* __restrict__ x,
    const float* __restrict__ w2,
    const float* __restrict__ g2, const float* __restrict__ b2,
    const float* __restrict__ m2, const float* __restrict__ v2,
    const float* __restrict__ w3,
    const float* __restrict__ g3, const float* __restrict__ b3,
    const float* __restrict__ m3, const float* __restrict__ v3,
    float* __restrict__ out)
{
    __shared__ float W[3][34 * 66];   // [row][col][ch] (+2 pad per col)
    __shared__ float T2[32 * 66];

    const int b  = blockIdx.x >> 7;
    const int h  = (blockIdx.x >> 1) & 63;
    const int wh = blockIdx.x & 1;
    const int wbase = wh << 5;
    const int tid = threadIdx.x;

#pragma unroll
    for (int r = 0; r < 3; ++r) {
        int hh = h + r - 1;
#pragma unroll
        for (int i = 0; i < 2; ++i) {
            int lin = (i << 8) + tid;
            if (lin < 272) {
                int wl = lin >> 3, cg = lin & 7;
                int wg = wbase + wl - 1;
                float* Wd = &W[r][wl * 66 + (cg << 3)];
                if (hh >= 0 && hh <= 63 && wg >= 0 && wg <= 63) {
                    size_t npos = (size_t)((b << 12) + (hh << 6) + wg);
                    uint4 v = *(const uint4*)(Obase + (npos << 6) + (cg << 3));
                    union { float f; unsigned u; } t;
                    t.u = v.x << 16;         Wd[0] = t.f;
                    t.u = v.x & 0xFFFF0000u; Wd[1] = t.f;
                    t.u = v.y << 16;         Wd[2] = t.f;
                    t.u = v.y & 0xFFFF0000u; Wd[3] = t.f;
                    t.u = v.z << 16;         Wd[4] = t.f;
                    t.u = v.z & 0xFFFF0000u; Wd[5] = t.f;
                    t.u = v.w << 16;         Wd[6] = t.f;
                    t.u = v.w & 0xFFFF0000u; Wd[7] = t.f;
                } else {
#pragma unroll
                    for (int j = 0; j < 8; ++j) Wd[j] = 0.f;
                }
            }
        }
    }
    __syncthreads();

    const int w32 = tid & 31, cq = tid >> 5;   // cq in [0,8): 8 channels
    float t8[8];
#pragma unroll
    for (int i = 0; i < 8; ++i) t8[i] = 0.f;

#pragma unroll
    for (int ky = 0; ky < 3; ++ky) {
#pragma unroll
        for (int kx = 0; kx < 3; ++kx) {
            const int k = ky * 3 + kx;
            const float* Wr = &W[ky][(w32 + kx) * 66 + (cq << 3)];
#pragma unroll
            for (int i = 0; i < 2; ++i) {
                float4 a = *(const float4*)(Wr + (i << 2));
                int c = (cq << 3) + (i << 2);
                t8[i * 4 + 0] = fmaf(w2[(c + 0) * 9 + k], a.x, t8[i * 4 + 0]);
                t8[i * 4 + 1] = fmaf(w2[(c + 1) * 9 + k], a.y, t8[i * 4 + 1]);
                t8[i * 4 + 2] = fmaf(w2[(c + 2) * 9 + k], a.z, t8[i * 4 + 2]);
                t8[i * 4 + 3] = fmaf(w2[(c + 3) * 9 + k], a.w, t8[i * 4 + 3]);
            }
        }
    }
#pragma unroll
    for (int i = 0; i < 8; ++i) {
        int c = (cq << 3) + i;
        float inv = g2[c] * rsqrtf(v2[c] + 1e-5f);
        float sh  = b2[c] - m2[c] * inv;
        T2[w32 * 66 + c] = fmaxf(fmaf(t8[i], inv, sh), 0.f);
    }
    __syncthreads();

    float rT[64];
#pragma unroll
    for (int c4 = 0; c4 < 16; ++c4)
        *(float4*)&rT[c4 << 2] = *(const float4*)&T2[w32 * 66 + (c4 << 2)];

    const int hw = (h << 6) + wbase + w32;
#pragma unroll 2
    for (int oo = 0; oo < 8; ++oo) {
        int o = (cq << 3) + oo;
        float inv = g3[o] * rsqrtf(v3[o] + 1e-5f);
        float sh  = b3[o] - m3[o] * inv;
        float acc = 0.f;
#pragma unroll
        for (int c = 0; c < 64; ++c) acc = fmaf(w3[o * 64 + c], rT[c], acc);
        size_t idx = (((size_t)((b << 6) + o)) << 12) + hw;
        out[idx] = fmaf(acc, inv, sh) + x[idx];
    }
}

// ---------------------------------------------------------------------------
extern "C" void kernel_launch(void* const* d_in, const int* in_sizes, int n_in,
                              void* d_out, int out_size, void* d_ws, size_t ws_size,
                              hipStream_t stream)
{
    const float* x  = (const float*)d_in[0];
    const float* w1 = (const float*)d_in[1];
    const float* g1 = (const float*)d_in[2];
    const float* b1 = (const float*)d_in[3];
    const float* m1 = (const float*)d_in[4];
    const float* v1 = (const float*)d_in[5];
    const float* w2 = (const float*)d_in[6];
    const float* g2 = (const float*)d_in[7];
    const float* b2 = (const float*)d_in[8];
    const float* m2 = (const float*)d_in[9];
    const float* v2 = (const float*)d_in[10];
    const float* w3 = (const float*)d_in[11];
    const float* g3 = (const float*)d_in[12];
    const float* b3 = (const float*)d_in[13];
    const float* m3 = (const float*)d_in[14];
    const float* v3 = (const float*)d_in[15];
    float* out = (float*)d_out;

    // ws: xTf 4MB | vbff 4MB | O 4MB (bf16, normalized)
    unsigned short* xTf  = (unsigned short*)d_ws;
    unsigned short* vbff = xTf + (size_t)8 * 4096 * 64;
    unsigned short* Obase = (unsigned short*)((char*)d_ws + (8u << 20));

    k_prep<<<1024, 256, 0, stream>>>(x, w1, g1, b1, m1, v1, xTf, vbff);
    k_attn<<<512, 1024, 0, stream>>>(xTf, vbff, Obase);
    k_post<<<1024, 256, 0, stream>>>(Obase, x, w2, g2, b2, m2, v2,
                                     w3, g3, b3, m3, v3, out);
}

// Round 17
// 181.580 us; speedup vs baseline: 2.7613x; 2.7613x over previous
//
#include <hip/hip_runtime.h>
#include <stdint.h>

typedef __attribute__((ext_vector_type(8)))  short s16x8;   // 8 x bf16
typedef __attribute__((ext_vector_type(16))) float f32x16;  // 32x32 MFMA acc
typedef __attribute__((ext_vector_type(2)))  unsigned u32x2;

union CvtI4 { int4 i; s16x8 s; };
union CvtU4 { uint4 u; s16x8 s; };

__device__ __forceinline__ unsigned f2bf(float f) {
    union { float f; unsigned u; } v; v.f = f;
    return (v.u + 0x7fffu + ((v.u >> 16) & 1u)) >> 16;     // RNE
}

// pack two f32 -> (bf16(lo) | bf16(hi)<<16), round-half-up (v12-verified idiom)
__device__ __forceinline__ unsigned packbf(float lo, float hi) {
    union { float f; unsigned u; } a0, a1;
    a0.f = lo; a1.f = hi;
    return __builtin_amdgcn_perm(a1.u + 0x8000u, a0.u + 0x8000u, 0x07060302u);
}

// ---------------------------------------------------------------------------
// k_prep v3: emits MFMA fragment-order layouts (for the barrier-free attn).
//   xTf:  [b][st=n>>5][kk=0..3][lane=0..63] 16B blocks; lane l = (n&31)+32*hb
//         holds bf16(x*QS) for row n, c = 16*kk + 8*hb + e  (A/B frag order).
//   vbff: [b][tile=n>>6][s][ksl][dl][lane] 16B blocks; lane l = (d&31)+32*hb
//         holds relu(bn1(w1.x)) for d-row, m = tile*64+(s*4+ksl*2+hb)*8+e.
// Values identical to the old xT/vbf; only addresses changed (verified maps).
// grid 1024 = (b, n0g, half), 256 thr.
// ---------------------------------------------------------------------------
__global__ __launch_bounds__(256) void k_prep(
    const float* __restrict__ x, const float* __restrict__ w1,
    const float* __restrict__ g1, const float* __restrict__ b1,
    const float* __restrict__ m1, const float* __restrict__ v1,
    unsigned short* __restrict__ xTf, unsigned short* __restrict__ vbff)
{
    __shared__ float X[64 * 65];   // [c][n] pad+1
    const int b    = blockIdx.x >> 7;
    const int n0g  = (blockIdx.x >> 1) & 63;
    const int n0   = n0g << 6;
    const int half = blockIdx.x & 1;
    const int tid  = threadIdx.x;
    const float QS = 0.42466090014400953f;   // sqrt(log2(e)/8)

    {
        const int r = tid >> 6, nn = tid & 63;
        const float* xb = x + (size_t)b * 262144 + n0 + nn;
#pragma unroll
        for (int cc = 0; cc < 16; ++cc) {
            int c = cc * 4 + r;
            X[c * 65 + nn] = xb[(size_t)c * 4096];
        }
    }
    __syncthreads();

    {   // xTf fragment write: thread (n8, c8) -> block (st, kk=c8>>1), lane n8+32*(c8&1)
        const int n8 = tid >> 3, c8 = tid & 7;
        const int kk = c8 >> 1, hb = c8 & 1;
        const int st = (n0g << 1) + half;         // global 32-row strip
        const int N  = (half << 5) + n8;          // local row in X
        unsigned u[4];
#pragma unroll
        for (int j = 0; j < 4; ++j) {
            unsigned lo = f2bf(X[(c8 * 8 + 2 * j) * 65 + N] * QS);
            unsigned hi = f2bf(X[(c8 * 8 + 2 * j + 1) * 65 + N] * QS);
            u[j] = lo | (hi << 16);
        }
        uint4 pk; pk.x = u[0]; pk.y = u[1]; pk.z = u[2]; pk.w = u[3];
        *(uint4*)(xTf + ((((size_t)((b << 7) + st) << 2) + kk) << 9)
                      + ((n8 + (hb << 5)) << 3)) = pk;
    }

    {   // vbff fragment write: V = relu(bn1(conv1x1)), d-half = half
        const int n = tid & 63, og = tid >> 6;
        float rX[64];
#pragma unroll
        for (int c = 0; c < 64; ++c) rX[c] = X[c * 65 + n];
        const int cn = n >> 3, e = n & 7;
        const int sS = cn >> 2, kslS = (cn >> 1) & 1, hb = cn & 1;
        unsigned short* vb = vbff +
            ((((size_t)((b << 6) + n0g) << 3) + (sS << 2) + (kslS << 1) + half) << 9) + e;
#pragma unroll 2
        for (int oo = 0; oo < 8; ++oo) {
            int o = (half << 5) + og * 8 + oo;
            float inv = g1[o] * rsqrtf(v1[o] + 1e-5f);
            float sh  = b1[o] - m1[o] * inv;
            float acc = 0.f;
#pragma unroll
            for (int c = 0; c < 64; ++c) acc = fmaf(w1[o * 64 + c], rX[c], acc);
            int lane = (og * 8 + oo) + (hb << 5);
            vb[lane << 3] = (unsigned short)f2bf(fmaxf(fmaf(acc, inv, sh), 0.f));
        }
    }
}

// ---------------------------------------------------------------------------
// k_attn v21 (FINAL, verified 49.2us @ R11): BARRIER-FREE streaming
// attention with fragment-order layouts. Each wave streams its Ak/Bv MFMA
// fragments directly from L2 via perfectly-coalesced 1KB loads; no LDS, no
// barriers in the main loop (conflicts == 0 measured). Waves free-run ->
// natural de-lockstep; L1/L2 absorb same-s fragment re-reads.
// Design-space map (R0-R16): barrier-phase schedules 53-57us; this 49.2;
// rotation null; ANY added cross-iteration register state spills (R12/13);
// 8 waves/SIMD impossible (live state ~100 VGPR > 64 cap; R16 spilled the
// accumulator tile, 1GB scratch traffic). This is the register-file-imposed
// ILP/TLP ceiling for the fused-softmax MFMA body.
// Geometry: grid 256 = (b=XCD, qg2 of 128 q), 16 waves,
// wave = (qd = s + 2*t2, par); wave processes tiles 2*it+par, it=0..31.
// Per tile: 8 coalesced loads -> QK(4 MFMA) -> exp2/pack -> permlane ->
// PV(4 MFMA). Epilogue: par/s-merge via 64KB LDS scratch.
// ---------------------------------------------------------------------------
__global__ __launch_bounds__(1024, 4) void k_attn(
    const unsigned short* __restrict__ xTf, const unsigned short* __restrict__ vbff,
    unsigned short* __restrict__ outO)
{
    __shared__ float scr[16384];      // 64KB epilogue scratch (unused in main loop)
    __shared__ float rsL[16][32];
    __shared__ float dnm[128];

    const int b   = blockIdx.x & 7;           // batch == XCD slice
    const int qg2 = blockIdx.x >> 3;          // 0..31 (128-q group)
    const int tid = threadIdx.x;
    const int w = tid >> 6, lane = tid & 63;
    const int l31 = lane & 31, half = lane >> 5;
    const int qbase = qg2 << 7;
    const int qd = w & 7, par = w >> 3;
    const int s  = qd & 1;     // m-strip (QK) / PV m-chunk group
    const int t2 = qd >> 1;    // n-slab (0..3), 32 q rows each

    // ---- Q fragments: blocks (st_q = qg2*4 + t2, kk) ----
    s16x8 Bq[4];
    {
        const unsigned short* qB = xTf +
            (((size_t)((b << 7) + (qg2 << 2) + t2)) << 11) + (lane << 3);
#pragma unroll
        for (int kk = 0; kk < 4; ++kk) {
            CvtI4 c; c.i = *(const int4*)(qB + (kk << 9));
            Bq[kk] = c.s;
        }
    }

    // ---- streaming bases: block idx = b*512 + T*8 + s*4 + j, T-stride 4096 ----
    const unsigned short* akB = xTf  + (((size_t)((b << 9) + (s << 2))) << 9) + (lane << 3);
    const unsigned short* bvB = vbff + (((size_t)((b << 9) + (s << 2))) << 9) + (lane << 3);

    f32x16 O[2];
#pragma unroll
    for (int dl = 0; dl < 2; ++dl)
#pragma unroll
        for (int r = 0; r < 16; ++r) O[dl][r] = 0.f;
    float rs = 0.f;

    // ================= main loop: 32 tiles, NO barriers =================
    for (int it = 0; it < 32; ++it) {
        const size_t toff = ((size_t)((it << 1) + par)) << 12;   // T*4096 ushorts

        int4 ar[4], br[4];
#pragma unroll
        for (int kk = 0; kk < 4; ++kk) ar[kk] = *(const int4*)(akB + (kk << 9) + toff);
#pragma unroll
        for (int j = 0; j < 4; ++j)    br[j]  = *(const int4*)(bvB + (j << 9) + toff);

        // ---- QK quadrant (s,t2) of tile T ----
        f32x16 S = {0.f,0.f,0.f,0.f,0.f,0.f,0.f,0.f,0.f,0.f,0.f,0.f,0.f,0.f,0.f,0.f};
        __builtin_amdgcn_s_setprio(1);
        {
            CvtI4 c0; c0.i = ar[0]; S = __builtin_amdgcn_mfma_f32_32x32x16_bf16(c0.s, Bq[0], S, 0, 0, 0);
            CvtI4 c1; c1.i = ar[1]; S = __builtin_amdgcn_mfma_f32_32x32x16_bf16(c1.s, Bq[1], S, 0, 0, 0);
            CvtI4 c2; c2.i = ar[2]; S = __builtin_amdgcn_mfma_f32_32x32x16_bf16(c2.s, Bq[2], S, 0, 0, 0);
            CvtI4 c3; c3.i = ar[3]; S = __builtin_amdgcn_mfma_f32_32x32x16_bf16(c3.s, Bq[3], S, 0, 0, 0);
        }
        __builtin_amdgcn_s_setprio(0);

        // ---- exp2 + pack to bf16 pairs (m-group q, lane-local in n) ----
        uint2 G[4];
#pragma unroll
        for (int q = 0; q < 4; ++q) {
            float p0 = __builtin_amdgcn_exp2f(S[4*q+0]);
            float p1 = __builtin_amdgcn_exp2f(S[4*q+1]);
            float p2 = __builtin_amdgcn_exp2f(S[4*q+2]);
            float p3 = __builtin_amdgcn_exp2f(S[4*q+3]);
            rs += (p0 + p1) + (p2 + p3);
            G[q].x = packbf(p0, p1);
            G[q].y = packbf(p2, p3);
        }

        // ---- PV: in-register P via permlane32_swap; B = streamed V frags ----
        __builtin_amdgcn_s_setprio(1);
#pragma unroll
        for (int ksl = 0; ksl < 2; ++ksl) {
            // swap(a,b) -> r.x = a.lo||b.lo (dw-low), r.y = a.hi||b.hi (dw-high)
            u32x2 r0 = __builtin_amdgcn_permlane32_swap(G[2*ksl].x, G[2*ksl+1].x, false, false);
            u32x2 r1 = __builtin_amdgcn_permlane32_swap(G[2*ksl].y, G[2*ksl+1].y, false, false);
            CvtU4 ac;
            ac.u.x = r0.x; ac.u.y = r1.x; ac.u.z = r0.y; ac.u.w = r1.y;
            const s16x8 Ap = ac.s;
            CvtI4 v0; v0.i = br[2*ksl + 0];
            CvtI4 v1; v1.i = br[2*ksl + 1];
            O[0] = __builtin_amdgcn_mfma_f32_32x32x16_bf16(Ap, v0.s, O[0], 0, 0, 0);
            O[1] = __builtin_amdgcn_mfma_f32_32x32x16_bf16(Ap, v1.s, O[1], 0, 0, 0);
        }
        __builtin_amdgcn_s_setprio(0);
    }

    // ================= epilogue: par-merge -> s-merge -> store =============
    float* scrK = scr;            // 8192 f32
    float* scrV = scr + 8192;     // 8192 f32

    rs += __shfl_xor(rs, 32);
    if (half == 0) rsL[w][l31] = rs;

    if (par == 1) {       // par-merge write: region qd (8 regions x 2048 f32)
        float* rg = (qd < 4) ? (scrK + (qd << 11)) : (scrV + ((qd - 4) << 11));
#pragma unroll
        for (int dl = 0; dl < 2; ++dl)
#pragma unroll
            for (int r = 0; r < 16; ++r)
                rg[(dl << 10) + (r << 6) + lane] = O[dl][r];
    }
    __syncthreads();

    if (tid < 128) {      // denom: 4 contributing waves per n-slab
        int tt = tid >> 5, n32 = tid & 31;
        dnm[tid] = (rsL[(tt << 1) + 0][n32] + rsL[(tt << 1) + 1][n32]) +
                   (rsL[(tt << 1) + 8][n32] + rsL[(tt << 1) + 9][n32]);
    }
    if (par == 0) {       // par-merge read
        float* rg = (qd < 4) ? (scrK + (qd << 11)) : (scrV + ((qd - 4) << 11));
#pragma unroll
        for (int dl = 0; dl < 2; ++dl)
#pragma unroll
            for (int r = 0; r < 16; ++r)
                O[dl][r] += rg[(dl << 10) + (r << 6) + lane];
    }
    __syncthreads();

    if (par == 0 && s == 1) {   // s-merge write: region t2 (4 x 2048 f32 in scrK)
#pragma unroll
        for (int dl = 0; dl < 2; ++dl)
#pragma unroll
            for (int r = 0; r < 16; ++r)
                scrK[(t2 << 11) + (dl << 10) + (r << 6) + lane] = O[dl][r];
    }
    __syncthreads();

    if (par == 0 && s == 0) {
        const int nb = (b << 12) + qbase;
#pragma unroll
        for (int dl = 0; dl < 2; ++dl)
#pragma unroll
            for (int r = 0; r < 16; ++r) {
                int rowoff = (r & 3) + ((r >> 2) << 3) + (half << 2);
                int n = (t2 << 5) + rowoff;
                float o = O[dl][r] + scrK[(t2 << 11) + (dl << 10) + (r << 6) + lane];
                outO[((size_t)(nb + n) << 6) + (dl << 5) + l31] =
                    (unsigned short)f2bf(o * (1.f / dnm[n]));
            }
    }
}

// ---------------------------------------------------------------------------
// k_post v2: w-half split. grid 1024 = (b, h, wh), 256 thr.
// ---------------------------------------------------------------------------
__global__ __launch_bounds__(256) void k_post(
    const unsigned short* __restrict__ Obase,
    const float* __restrict__ x,
    const float* __restrict__ w2,
    const float* __restrict__ g2, const float* __restrict__ b2,
    const float* __restrict__ m2, const float* __restrict__ v2,
    const float* __restrict__ w3,
    const float* __restrict__ g3, const float* __restrict__ b3,
    const float* __restrict__ m3, const float* __restrict__ v3,
    float* __restrict__ out)
{
    __shared__ float W[3][34 * 66];   // [row][col][ch] (+2 pad per col)
    __shared__ float T2[32 * 66];

    const int b  = blockIdx.x >> 7;
    const int h  = (blockIdx.x >> 1) & 63;
    const int wh = blockIdx.x & 1;
    const int wbase = wh << 5;
    const int tid = threadIdx.x;

#pragma unroll
    for (int r = 0; r < 3; ++r) {
        int hh = h + r - 1;
#pragma unroll
        for (int i = 0; i < 2; ++i) {
            int lin = (i << 8) + tid;
            if (lin < 272) {
                int wl = lin >> 3, cg = lin & 7;
                int wg = wbase + wl - 1;
                float* Wd = &W[r][wl * 66 + (cg << 3)];
                if (hh >= 0 && hh <= 63 && wg >= 0 && wg <= 63) {
                    size_t npos = (size_t)((b << 12) + (hh << 6) + wg);
                    uint4 v = *(const uint4*)(Obase + (npos << 6) + (cg << 3));
                    union { float f; unsigned u; } t;
                    t.u = v.x << 16;         Wd[0] = t.f;
                    t.u = v.x & 0xFFFF0000u; Wd[1] = t.f;
                    t.u = v.y << 16;         Wd[2] = t.f;
                    t.u = v.y & 0xFFFF0000u; Wd[3] = t.f;
                    t.u = v.z << 16;         Wd[4] = t.f;
                    t.u = v.z & 0xFFFF0000u; Wd[5] = t.f;
                    t.u = v.w << 16;         Wd[6] = t.f;
                    t.u = v.w & 0xFFFF0000u; Wd[7] = t.f;
                } else {
#pragma unroll
                    for (int j = 0; j < 8; ++j) Wd[j] = 0.f;
                }
            }
        }
    }
    __syncthreads();

    const int w32 = tid & 31, cq = tid >> 5;   // cq in [0,8): 8 channels
    float t8[8];
#pragma unroll
    for (int i = 0; i < 8; ++i) t8[i] = 0.f;

#pragma unroll
    for (int ky = 0; ky < 3; ++ky) {
#pragma unroll
        for (int kx = 0; kx < 3; ++kx) {
            const int k = ky * 3 + kx;
            const float* Wr = &W[ky][(w32 + kx) * 66 + (cq << 3)];
#pragma unroll
            for (int i = 0; i < 2; ++i) {
                float4 a = *(const float4*)(Wr + (i << 2));
                int c = (cq << 3) + (i << 2);
                t8[i * 4 + 0] = fmaf(w2[(c + 0) * 9 + k], a.x, t8[i * 4 + 0]);
                t8[i * 4 + 1] = fmaf(w2[(c + 1) * 9 + k], a.y, t8[i * 4 + 1]);
                t8[i * 4 + 2] = fmaf(w2[(c + 2) * 9 + k], a.z, t8[i * 4 + 2]);
                t8[i * 4 + 3] = fmaf(w2[(c + 3) * 9 + k], a.w, t8[i * 4 + 3]);
            }
        }
    }
#pragma unroll
    for (int i = 0; i < 8; ++i) {
        int c = (cq << 3) + i;
        float inv = g2[c] * rsqrtf(v2[c] + 1e-5f);
        float sh  = b2[c] - m2[c] * inv;
        T2[w32 * 66 + c] = fmaxf(fmaf(t8[i], inv, sh), 0.f);
    }
    __syncthreads();

    float rT[64];
#pragma unroll
    for (int c4 = 0; c4 < 16; ++c4)
        *(float4*)&rT[c4 << 2] = *(const float4*)&T2[w32 * 66 + (c4 << 2)];

    const int hw = (h << 6) + wbase + w32;
#pragma unroll 2
    for (int oo = 0; oo < 8; ++oo) {
        int o = (cq << 3) + oo;
        float inv = g3[o] * rsqrtf(v3[o] + 1e-5f);
        float sh  = b3[o] - m3[o] * inv;
        float acc = 0.f;
#pragma unroll
        for (int c = 0; c < 64; ++c) acc = fmaf(w3[o * 64 + c], rT[c], acc);
        size_t idx = (((size_t)((b << 6) + o)) << 12) + hw;
        out[idx] = fmaf(acc, inv, sh) + x[idx];
    }
}

// ---------------------------------------------------------------------------
extern "C" void kernel_launch(void* const* d_in, const int* in_sizes, int n_in,
                              void* d_out, int out_size, void* d_ws, size_t ws_size,
                              hipStream_t stream)
{
    const float* x  = (const float*)d_in[0];
    const float* w1 = (const float*)d_in[1];
    const float* g1 = (const float*)d_in[2];
    const float* b1 = (const float*)d_in[3];
    const float* m1 = (const float*)d_in[4];
    const float* v1 = (const float*)d_in[5];
    const float* w2 = (const float*)d_in[6];
    const float* g2 = (const float*)d_in[7];
    const float* b2 = (const float*)d_in[8];
    const float* m2 = (const float*)d_in[9];
    const float* v2 = (const float*)d_in[10];
    const float* w3 = (const float*)d_in[11];
    const float* g3 = (const float*)d_in[12];
    const float* b3 = (const float*)d_in[13];
    const float* m3 = (const float*)d_in[14];
    const float* v3 = (const float*)d_in[15];
    float* out = (float*)d_out;

    // ws: xTf 4MB | vbff 4MB | O 4MB (bf16, normalized)
    unsigned short* xTf  = (unsigned short*)d_ws;
    unsigned short* vbff = xTf + (size_t)8 * 4096 * 64;
    unsigned short* Obase = (unsigned short*)((char*)d_ws + (8u << 20));

    k_prep<<<1024, 256, 0, stream>>>(x, w1, g1, b1, m1, v1, xTf, vbff);
    k_attn<<<256, 1024, 0, stream>>>(xTf, vbff, Obase);
    k_post<<<1024, 256, 0, stream>>>(Obase, x, w2, g2, b2, m2, v2,
                                     w3, g3, b3, m3, v3, out);
}